// Round 2
// baseline (1051.565 us; speedup 1.0000x reference)
//
#include <hip/hip_runtime.h>
#include <hip/hip_bf16.h>

typedef __attribute__((ext_vector_type(8))) short bf16x8;
typedef __attribute__((ext_vector_type(4))) float f32x4;

#define F 128
#define HOPS 5

__device__ __forceinline__ float b2f(__hip_bfloat16 h) { return __bfloat162float(h); }
__device__ __forceinline__ __hip_bfloat16 f2b(float f) { return __float2bfloat16(f); }

__device__ __forceinline__ float load_in(const void* p, size_t i, int isbf) {
    return isbf ? __bfloat162float(((const __hip_bfloat16*)p)[i]) : ((const float*)p)[i];
}

// ---------------- dtype detection (one block) ----------------
__global__ void detect_k(const unsigned int* __restrict__ w, int* flag) {
    __shared__ int cnt[256];
    int t = threadIdx.x;
    unsigned int x = w[t * 97];
    int e_low = (x >> 7) & 0xFF;   // exponent field of low-half bf16
    cnt[t] = (e_low >= 110 && e_low <= 135) ? 1 : 0;
    __syncthreads();
    for (int s = 128; s > 0; s >>= 1) {
        if (t < s) cnt[t] += cnt[t + s];
        __syncthreads();
    }
    if (t == 0) flag[0] = (cnt[0] >= 160) ? 1 : 0;
}

__global__ void cvt_w_k(const void* __restrict__ w, __hip_bfloat16* __restrict__ o,
                        int n, const int* __restrict__ flag) {
    int i = blockIdx.x * blockDim.x + threadIdx.x;
    if (i < n) {
        o[i] = flag[0] ? ((const __hip_bfloat16*)w)[i] : f2b(((const float*)w)[i]);
    }
}

// ---------------- graph build ----------------
__global__ void zero_ints_k(int* a, int n) {
    int i = blockIdx.x * blockDim.x + threadIdx.x;
    if (i < n) a[i] = 0;
}

__global__ void degree_k(const int* __restrict__ src, const int* __restrict__ dst,
                         int* in_cnt, int* out_cnt, int E) {
    int i = blockIdx.x * blockDim.x + threadIdx.x;
    if (i < E) {
        atomicAdd(&in_cnt[dst[i]], 1);
        atomicAdd(&out_cnt[src[i]], 1);
    }
}

__global__ void norms_k(const int* __restrict__ in_cnt, const int* __restrict__ out_cnt,
                        float* head_norm, float* tail_norm, float* log_in, int N) {
    int i = blockIdx.x * blockDim.x + threadIdx.x;
    if (i < N) {
        float id = fmaxf((float)in_cnt[i], 1.0f);
        float od = fmaxf((float)out_cnt[i], 1.0f);
        head_norm[i] = rsqrtf(od);
        tail_norm[i] = sqrtf(id);
        log_in[i] = log1pf(id);
    }
}

__global__ void scan_k(const int* __restrict__ cnt, int* row_ptr, int N) {
    __shared__ int part[1024];
    int t = threadIdx.x;
    int chunk = (N + 1023) >> 10;
    int s = t * chunk, e = min(s + chunk, N);
    int sum = 0;
    for (int i = s; i < e; ++i) sum += cnt[i];
    part[t] = sum;
    __syncthreads();
    for (int off = 1; off < 1024; off <<= 1) {
        int v = (t >= off) ? part[t - off] : 0;
        __syncthreads();
        part[t] += v;
        __syncthreads();
    }
    int run = (t > 0) ? part[t - 1] : 0;
    for (int i = s; i < e; ++i) { row_ptr[i] = run; run += cnt[i]; }
    if (t == 1023) row_ptr[N] = part[1023];
}

__global__ void scatter_k(const int* __restrict__ src, const int* __restrict__ dst,
                          const int* __restrict__ row_ptr, int* cursor,
                          int* csr_src, int* csr_dst, int E) {
    int i = blockIdx.x * blockDim.x + threadIdx.x;
    if (i < E) {
        int d = dst[i];
        int p = row_ptr[d] + atomicAdd(&cursor[d], 1);
        csr_src[p] = src[i];
        csr_dst[p] = d;
    }
}

// ---------------- LayerNorms ----------------
__global__ void ln1_k(const void* __restrict__ x, const void* __restrict__ g,
                      const void* __restrict__ b, const int* __restrict__ flag,
                      __hip_bfloat16* __restrict__ y, int N) {
    int w = blockIdx.x * (blockDim.x >> 6) + (threadIdx.x >> 6);
    if (w >= N) return;
    int isbf = flag[0];
    int t = threadIdx.x & 63;
    float v0 = load_in(x, (size_t)w * F + t, isbf);
    float v1 = load_in(x, (size_t)w * F + t + 64, isbf);
    float s = v0 + v1, sq = v0 * v0 + v1 * v1;
    for (int m = 1; m < 64; m <<= 1) { s += __shfl_xor(s, m, 64); sq += __shfl_xor(sq, m, 64); }
    float mu = s * (1.0f / F);
    float var = fmaxf(sq * (1.0f / F) - mu * mu, 0.0f);
    float r = rsqrtf(var + 1e-5f);
    y[(size_t)w * F + t]      = f2b((v0 - mu) * r * load_in(g, t, isbf) + load_in(b, t, isbf));
    y[(size_t)w * F + t + 64] = f2b((v1 - mu) * r * load_in(g, t + 64, isbf) + load_in(b, t + 64, isbf));
}

__global__ void ln2_k(const float* __restrict__ x, const void* __restrict__ g,
                      const void* __restrict__ b, const int* __restrict__ flag,
                      __hip_bfloat16* __restrict__ y, int N) {
    int w = blockIdx.x * (blockDim.x >> 6) + (threadIdx.x >> 6);
    if (w >= N) return;
    int isbf = flag[0];
    int t = threadIdx.x & 63;
    float v0 = x[(size_t)w * F + t], v1 = x[(size_t)w * F + t + 64];
    float s = v0 + v1, sq = v0 * v0 + v1 * v1;
    for (int m = 1; m < 64; m <<= 1) { s += __shfl_xor(s, m, 64); sq += __shfl_xor(sq, m, 64); }
    float mu = s * (1.0f / F);
    float var = fmaxf(sq * (1.0f / F) - mu * mu, 0.0f);
    float r = rsqrtf(var + 1e-5f);
    y[(size_t)w * F + t]      = f2b((v0 - mu) * r * load_in(g, t, isbf) + load_in(b, t, isbf));
    y[(size_t)w * F + t + 64] = f2b((v1 - mu) * r * load_in(g, t + 64, isbf) + load_in(b, t + 64, isbf));
}

// ---------------- projection GEMM ----------------
__global__ void proj_gemm_k(const __hip_bfloat16* __restrict__ X,
                            const __hip_bfloat16* __restrict__ Wh,
                            const __hip_bfloat16* __restrict__ Wt,
                            const __hip_bfloat16* __restrict__ We,
                            const float* __restrict__ head_norm,
                            __hip_bfloat16* __restrict__ fh,
                            __hip_bfloat16* __restrict__ ft,
                            float* __restrict__ fe, int N) {
    int mt = blockIdx.x, nt = blockIdx.y;
    int lane = threadIdx.x & 63;
    int lr = lane & 15, quad = lane >> 4;
    int wsel = nt >> 3;
    const __hip_bfloat16* W = (wsel == 0) ? Wh : (wsel == 1) ? Wt : We;
    int ncol = (nt & 7) * 16 + lr;
    int mrow = mt * 16 + lr;
    if (mrow >= N) mrow = N - 1;
    f32x4 acc = {0.f, 0.f, 0.f, 0.f};
    const __hip_bfloat16* ar = X + (size_t)mrow * F + quad * 8;
    const __hip_bfloat16* br = W + (size_t)ncol * F + quad * 8;
    for (int kk = 0; kk < 4; ++kk) {
        bf16x8 af = *reinterpret_cast<const bf16x8*>(ar + kk * 32);
        bf16x8 bv = *reinterpret_cast<const bf16x8*>(br + kk * 32);
        acc = __builtin_amdgcn_mfma_f32_16x16x32_bf16(af, bv, acc, 0, 0, 0);
    }
    for (int r = 0; r < 4; ++r) {
        int row = mt * 16 + quad * 4 + r;
        if (row >= N) continue;
        float v = acc[r] * head_norm[row];
        size_t idx = (size_t)row * F + ncol;
        if (wsel == 0) fh[idx] = f2b(v);
        else if (wsel == 1) ft[idx] = f2b(v);
        else fe[idx] = v;
    }
}

// ---------------- edge attention ----------------
__global__ void attn_k(const int* __restrict__ csr_src, const int* __restrict__ csr_dst,
                       const __hip_bfloat16* __restrict__ fh, const __hip_bfloat16* __restrict__ ft,
                       const void* __restrict__ attn, const int* __restrict__ flag,
                       const float* __restrict__ log_in,
                       float* __restrict__ e_buf, int E) {
    int isbf = flag[0];
    int t = threadIdx.x & 63;
    int wid = (blockIdx.x * blockDim.x + threadIdx.x) >> 6;
    int nw = (gridDim.x * blockDim.x) >> 6;
    float a0 = load_in(attn, t, isbf), a1 = load_in(attn, t + 64, isbf);
    int g = t >> 4;
    for (int pos = wid; pos < E; pos += nw) {
        int s = csr_src[pos], v = csr_dst[pos];
        float p0 = b2f(fh[(size_t)s * F + t]) * b2f(ft[(size_t)v * F + t]);
        float p1 = b2f(fh[(size_t)s * F + t + 64]) * b2f(ft[(size_t)v * F + t + 64]);
        p0 = (p0 > 0.f ? p0 : 0.2f * p0) * a0;
        p1 = (p1 > 0.f ? p1 : 0.2f * p1) * a1;
        for (int m = 1; m < 16; m <<= 1) { p0 += __shfl_xor(p0, m, 64); p1 += __shfl_xor(p1, m, 64); }
        if ((t & 15) == 0) {
            float sc = log_in[v] * (1.0f / 16.0f);
            e_buf[(size_t)pos * 8 + g] = p0 * sc;
            e_buf[(size_t)pos * 8 + g + 4] = p1 * sc;
        }
    }
}

__global__ void softmax_k(float* e_buf, const int* __restrict__ row_ptr, int N) {
    int tid = blockIdx.x * blockDim.x + threadIdx.x;
    if (tid >= N * 8) return;
    int v = tid >> 3, h = tid & 7;
    int b = row_ptr[v], e = row_ptr[v + 1];
    float mx = -1e30f;
    for (int p = b; p < e; ++p) mx = fmaxf(mx, e_buf[(size_t)p * 8 + h]);
    float sum = 0.f;
    for (int p = b; p < e; ++p) sum += expf(e_buf[(size_t)p * 8 + h] - mx);
    float inv = 1.0f / fmaxf(sum, 1e-30f);
    for (int p = b; p < e; ++p) e_buf[(size_t)p * 8 + h] = expf(e_buf[(size_t)p * 8 + h] - mx) * inv;
}

// ---------------- diffusion hop ----------------
__global__ void hop_k(const float* __restrict__ gsrc, const float* __restrict__ a_buf,
                      const int* __restrict__ csr_src, const int* __restrict__ row_ptr,
                      const float* __restrict__ tail_norm, const float* __restrict__ head_norm,
                      const float* __restrict__ fe, const void* __restrict__ feat,
                      const int* __restrict__ flag,
                      float* __restrict__ out, int last, int N) {
    int w = blockIdx.x * (blockDim.x >> 6) + (threadIdx.x >> 6);
    if (w >= N) return;
    int t = threadIdx.x & 63;
    int b = row_ptr[w], e = row_ptr[w + 1];
    int h0 = t >> 4;
    float acc0 = 0.f, acc1 = 0.f;
    for (int p = b; p < e; ++p) {
        int s = csr_src[p];
        float a0 = a_buf[(size_t)p * 8 + h0];
        float a1 = a_buf[(size_t)p * 8 + h0 + 4];
        acc0 += gsrc[(size_t)s * F + t] * a0;
        acc1 += gsrc[(size_t)s * F + t + 64] * a1;
    }
    float tl = tail_norm[w];
    float r0 = 0.9f * tl * acc0 + 0.1f * fe[(size_t)w * F + t];
    float r1 = 0.9f * tl * acc1 + 0.1f * fe[(size_t)w * F + t + 64];
    if (last) {
        int isbf = flag[0];
        out[(size_t)w * F + t]      = r0 + load_in(feat, (size_t)w * F + t, isbf);
        out[(size_t)w * F + t + 64] = r1 + load_in(feat, (size_t)w * F + t + 64, isbf);
    } else {
        float hn = head_norm[w];
        out[(size_t)w * F + t] = r0 * hn;
        out[(size_t)w * F + t + 64] = r1 * hn;
    }
}

// ---------------- FFN ----------------
__global__ void ff1_k(const __hip_bfloat16* __restrict__ Y, const __hip_bfloat16* __restrict__ W1,
                      const void* __restrict__ b1, const int* __restrict__ flag,
                      __hip_bfloat16* __restrict__ T1, int N) {
    int mt = blockIdx.x, nt = blockIdx.y;
    int lane = threadIdx.x & 63;
    int lr = lane & 15, quad = lane >> 4;
    int mrow = mt * 16 + lr;
    if (mrow >= N) mrow = N - 1;
    int ncol = nt * 16 + lr;
    f32x4 acc = {0.f, 0.f, 0.f, 0.f};
    const __hip_bfloat16* ar = Y + (size_t)mrow * F + quad * 8;
    const __hip_bfloat16* br = W1 + (size_t)ncol * F + quad * 8;
    for (int kk = 0; kk < 4; ++kk) {
        bf16x8 af = *reinterpret_cast<const bf16x8*>(ar + kk * 32);
        bf16x8 bv = *reinterpret_cast<const bf16x8*>(br + kk * 32);
        acc = __builtin_amdgcn_mfma_f32_16x16x32_bf16(af, bv, acc, 0, 0, 0);
    }
    float bias = load_in(b1, ncol, flag[0]);
    for (int r = 0; r < 4; ++r) {
        int row = mt * 16 + quad * 4 + r;
        if (row >= N) continue;
        float v = acc[r] + bias;
        v = v > 0.f ? v : 0.f;
        T1[(size_t)row * 512 + ncol] = f2b(v);
    }
}

__global__ void ff2_k(const __hip_bfloat16* __restrict__ T1, const __hip_bfloat16* __restrict__ W2,
                      const void* __restrict__ b2v, const float* __restrict__ rst,
                      const int* __restrict__ flag, void* __restrict__ out, int N) {
    int mt = blockIdx.x, nt = blockIdx.y;
    int lane = threadIdx.x & 63;
    int lr = lane & 15, quad = lane >> 4;
    int mrow = mt * 16 + lr;
    if (mrow >= N) mrow = N - 1;
    int ncol = nt * 16 + lr;
    f32x4 acc = {0.f, 0.f, 0.f, 0.f};
    const __hip_bfloat16* ar = T1 + (size_t)mrow * 512 + quad * 8;
    const __hip_bfloat16* br = W2 + (size_t)ncol * 512 + quad * 8;
    for (int kk = 0; kk < 16; ++kk) {
        bf16x8 af = *reinterpret_cast<const bf16x8*>(ar + kk * 32);
        bf16x8 bv = *reinterpret_cast<const bf16x8*>(br + kk * 32);
        acc = __builtin_amdgcn_mfma_f32_16x16x32_bf16(af, bv, acc, 0, 0, 0);
    }
    int isbf = flag[0];
    float bias = load_in(b2v, ncol, isbf);
    for (int r = 0; r < 4; ++r) {
        int row = mt * 16 + quad * 4 + r;
        if (row >= N) continue;
        float v = acc[r] + bias + rst[(size_t)row * F + ncol];
        size_t idx = (size_t)row * F + ncol;
        if (isbf) ((__hip_bfloat16*)out)[idx] = f2b(v);
        else ((float*)out)[idx] = v;
    }
}

extern "C" void kernel_launch(void* const* d_in, const int* in_sizes, int n_in,
                              void* d_out, int out_size, void* d_ws, size_t ws_size,
                              hipStream_t stream) {
    if (n_in < 15) return;
    const void* feat = d_in[0];
    const int* src = (const int*)d_in[1];
    const int* dst = (const int*)d_in[2];
    const void* w_head = d_in[3];
    const void* w_tail = d_in[4];
    const void* w_ent  = d_in[5];
    const void* attn   = d_in[6];
    const void* ln1_g  = d_in[7];
    const void* ln1_b  = d_in[8];
    const void* ln2_g  = d_in[9];
    const void* ln2_b  = d_in[10];
    const void* ff_w1  = d_in[11];
    const void* ff_b1  = d_in[12];
    const void* ff_w2  = d_in[13];
    const void* ff_b2  = d_in[14];

    const int N = in_sizes[0] / F;
    const int E = in_sizes[1];
    (void)out_size;

    char* base = (char*)d_ws;
    size_t off = 0;
    auto alloc = [&](size_t bytes) -> void* {
        void* r = base + off;
        off += (bytes + 255) & ~(size_t)255;
        return r;
    };
    int* cnt3      = (int*)alloc((size_t)3 * N * 4);
    int* in_cnt = cnt3, * out_cnt = cnt3 + N, * cursor = cnt3 + 2 * N;
    int* row_ptr   = (int*)alloc((size_t)(N + 1) * 4);
    int* flag      = (int*)alloc(256);
    float* head_norm = (float*)alloc((size_t)N * 4);
    float* tail_norm = (float*)alloc((size_t)N * 4);
    float* log_in    = (float*)alloc((size_t)N * 4);
    int* csr_src   = (int*)alloc((size_t)E * 4);
    int* csr_dst   = (int*)alloc((size_t)E * 4);
    __hip_bfloat16* wh_bf = (__hip_bfloat16*)alloc((size_t)F * F * 2);
    __hip_bfloat16* wt_bf = (__hip_bfloat16*)alloc((size_t)F * F * 2);
    __hip_bfloat16* we_bf = (__hip_bfloat16*)alloc((size_t)F * F * 2);
    __hip_bfloat16* w1_bf = (__hip_bfloat16*)alloc((size_t)512 * F * 2);
    __hip_bfloat16* w2_bf = (__hip_bfloat16*)alloc((size_t)F * 512 * 2);
    __hip_bfloat16* x_bf = (__hip_bfloat16*)alloc((size_t)N * F * 2);   // t1 alias base
    __hip_bfloat16* fh   = (__hip_bfloat16*)alloc((size_t)N * F * 2);
    __hip_bfloat16* ftb  = (__hip_bfloat16*)alloc((size_t)N * F * 2);
    float* e_a = (float*)alloc((size_t)E * 8 * 4);
    __hip_bfloat16* t1 = x_bf;   // N*512 bf16 = 51.2MB fits in x_bf+fh+ftb+e_a (58.9MB)
    float* fe  = (float*)alloc((size_t)N * F * 4);
    float* hA  = (float*)alloc((size_t)N * F * 4);
    float* hB  = (float*)alloc((size_t)N * F * 4);
    float* rst = (float*)alloc((size_t)N * F * 4);
    __hip_bfloat16* y_bf = (__hip_bfloat16*)hA;   // ln2 out reuses hA (dead after hops)
    if (off > ws_size) return;

    const int Mt = (N + 15) / 16;
    const int nodeBlocks = (N + 3) / 4;

    detect_k<<<1, 256, 0, stream>>>((const unsigned int*)feat, flag);
    cvt_w_k<<<(F * F + 255) / 256, 256, 0, stream>>>(w_head, wh_bf, F * F, flag);
    cvt_w_k<<<(F * F + 255) / 256, 256, 0, stream>>>(w_tail, wt_bf, F * F, flag);
    cvt_w_k<<<(F * F + 255) / 256, 256, 0, stream>>>(w_ent, we_bf, F * F, flag);
    cvt_w_k<<<(512 * F + 255) / 256, 256, 0, stream>>>(ff_w1, w1_bf, 512 * F, flag);
    cvt_w_k<<<(512 * F + 255) / 256, 256, 0, stream>>>(ff_w2, w2_bf, 512 * F, flag);

    zero_ints_k<<<(3 * N + 255) / 256, 256, 0, stream>>>(cnt3, 3 * N);
    degree_k<<<(E + 255) / 256, 256, 0, stream>>>(src, dst, in_cnt, out_cnt, E);
    norms_k<<<(N + 255) / 256, 256, 0, stream>>>(in_cnt, out_cnt, head_norm, tail_norm, log_in, N);
    scan_k<<<1, 1024, 0, stream>>>(in_cnt, row_ptr, N);
    scatter_k<<<(E + 255) / 256, 256, 0, stream>>>(src, dst, row_ptr, cursor, csr_src, csr_dst, E);

    ln1_k<<<nodeBlocks, 256, 0, stream>>>(feat, ln1_g, ln1_b, flag, x_bf, N);
    proj_gemm_k<<<dim3(Mt, 24), 64, 0, stream>>>(x_bf, wh_bf, wt_bf, we_bf, head_norm, fh, ftb, fe, N);

    attn_k<<<2048, 256, 0, stream>>>(csr_src, csr_dst, fh, ftb, attn, flag, log_in, e_a, E);
    softmax_k<<<(N * 8 + 255) / 256, 256, 0, stream>>>(e_a, row_ptr, N);

    const float* gsrc = fe;
    float* bufs[2] = {hA, hB};
    for (int hop = 0; hop < HOPS; ++hop) {
        int last = (hop == HOPS - 1);
        float* dstbuf = last ? rst : bufs[hop & 1];
        hop_k<<<nodeBlocks, 256, 0, stream>>>(gsrc, e_a, csr_src, row_ptr, tail_norm,
                                              head_norm, fe, feat, flag, dstbuf, last, N);
        gsrc = dstbuf;
    }

    ln2_k<<<nodeBlocks, 256, 0, stream>>>(rst, ln2_g, ln2_b, flag, y_bf, N);
    ff1_k<<<dim3(Mt, 32), 64, 0, stream>>>(y_bf, w1_bf, ff_b1, flag, t1, N);
    ff2_k<<<dim3(Mt, 8), 64, 0, stream>>>(t1, w2_bf, ff_b2, rst, flag, d_out, N);
}

// Round 3
// 880.296 us; speedup vs baseline: 1.1946x; 1.1946x over previous
//
#include <hip/hip_runtime.h>
#include <hip/hip_bf16.h>

typedef __attribute__((ext_vector_type(8))) short bf16x8;
typedef __attribute__((ext_vector_type(4))) float f32x4;
typedef unsigned int uint32;

#define F 128
#define HOPS 5

__device__ __forceinline__ float b2f(__hip_bfloat16 h) { return __bfloat162float(h); }
__device__ __forceinline__ __hip_bfloat16 f2b(float f) { return __float2bfloat16(f); }

__device__ __forceinline__ float load_in(const void* p, size_t i, int isbf) {
    return isbf ? __bfloat162float(((const __hip_bfloat16*)p)[i]) : ((const float*)p)[i];
}

// bf16-pair helpers (exact decode via bit shift; encode via RNE)
__device__ __forceinline__ float bflo(uint32 u) { union { uint32 i; float f; } v; v.i = u << 16; return v.f; }
__device__ __forceinline__ float bfhi(uint32 u) { union { uint32 i; float f; } v; v.i = u & 0xffff0000u; return v.f; }
__device__ __forceinline__ uint32 packbf2(float a, float b) {
    __hip_bfloat16 ha = f2b(a), hb = f2b(b);
    unsigned short ua = *(unsigned short*)&ha, ub = *(unsigned short*)&hb;
    return ((uint32)ub << 16) | ua;
}

// ---------------- dtype detection ----------------
__global__ void detect_k(const uint32* __restrict__ w, int* flag) {
    __shared__ int cnt[256];
    int t = threadIdx.x;
    uint32 x = w[t * 97];
    int e_low = (x >> 7) & 0xFF;
    cnt[t] = (e_low >= 110 && e_low <= 135) ? 1 : 0;
    __syncthreads();
    for (int s = 128; s > 0; s >>= 1) {
        if (t < s) cnt[t] += cnt[t + s];
        __syncthreads();
    }
    if (t == 0) flag[0] = (cnt[0] >= 160) ? 1 : 0;
}

__global__ void cvt_w_k(const void* __restrict__ w, __hip_bfloat16* __restrict__ o,
                        int n, const int* __restrict__ flag) {
    int i = blockIdx.x * blockDim.x + threadIdx.x;
    if (i < n) o[i] = flag[0] ? ((const __hip_bfloat16*)w)[i] : f2b(((const float*)w)[i]);
}

__global__ void cvt_f_k(const void* __restrict__ w, float* __restrict__ o,
                        int n, const int* __restrict__ flag) {
    int i = blockIdx.x * blockDim.x + threadIdx.x;
    if (i < n) o[i] = load_in(w, i, flag[0]);
}

// ---------------- graph build ----------------
__global__ void zero_ints_k(int* a, int n) {
    int i = blockIdx.x * blockDim.x + threadIdx.x;
    if (i < n) a[i] = 0;
}

__global__ void degree_k(const int* __restrict__ src, const int* __restrict__ dst,
                         int* in_cnt, int* out_cnt, int E) {
    int i = blockIdx.x * blockDim.x + threadIdx.x;
    if (i < E) {
        atomicAdd(&in_cnt[dst[i]], 1);
        atomicAdd(&out_cnt[src[i]], 1);
    }
}

__global__ void norms_k(const int* __restrict__ in_cnt, const int* __restrict__ out_cnt,
                        float* head_norm, float* tail_norm, float* log_in, int N) {
    int i = blockIdx.x * blockDim.x + threadIdx.x;
    if (i < N) {
        float id = fmaxf((float)in_cnt[i], 1.0f);
        float od = fmaxf((float)out_cnt[i], 1.0f);
        head_norm[i] = rsqrtf(od);
        tail_norm[i] = sqrtf(id);
        log_in[i] = log1pf(id);
    }
}

__global__ void scan_k(const int* __restrict__ cnt, int* row_ptr, int N) {
    __shared__ int part[1024];
    int t = threadIdx.x;
    int chunk = (N + 1023) >> 10;
    int s = t * chunk, e = min(s + chunk, N);
    int sum = 0;
    for (int i = s; i < e; ++i) sum += cnt[i];
    part[t] = sum;
    __syncthreads();
    for (int off = 1; off < 1024; off <<= 1) {
        int v = (t >= off) ? part[t - off] : 0;
        __syncthreads();
        part[t] += v;
        __syncthreads();
    }
    int run = (t > 0) ? part[t - 1] : 0;
    for (int i = s; i < e; ++i) { row_ptr[i] = run; run += cnt[i]; }
    if (t == 1023) row_ptr[N] = part[1023];
}

__global__ void scatter_k(const int* __restrict__ src, const int* __restrict__ dst,
                          const int* __restrict__ row_ptr, int* cursor,
                          int* csr_src, int E) {
    int i = blockIdx.x * blockDim.x + threadIdx.x;
    if (i < E) {
        int d = dst[i];
        int p = row_ptr[d] + atomicAdd(&cursor[d], 1);
        csr_src[p] = src[i];
    }
}

// ---------------- LayerNorms ----------------
__global__ void ln1_k(const void* __restrict__ x, const void* __restrict__ g,
                      const void* __restrict__ b, const int* __restrict__ flag,
                      __hip_bfloat16* __restrict__ y, int N) {
    int w = blockIdx.x * (blockDim.x >> 6) + (threadIdx.x >> 6);
    if (w >= N) return;
    int isbf = flag[0];
    int t = threadIdx.x & 63;
    float v0 = load_in(x, (size_t)w * F + t, isbf);
    float v1 = load_in(x, (size_t)w * F + t + 64, isbf);
    float s = v0 + v1, sq = v0 * v0 + v1 * v1;
    for (int m = 1; m < 64; m <<= 1) { s += __shfl_xor(s, m, 64); sq += __shfl_xor(sq, m, 64); }
    float mu = s * (1.0f / F);
    float var = fmaxf(sq * (1.0f / F) - mu * mu, 0.0f);
    float r = rsqrtf(var + 1e-5f);
    y[(size_t)w * F + t]      = f2b((v0 - mu) * r * load_in(g, t, isbf) + load_in(b, t, isbf));
    y[(size_t)w * F + t + 64] = f2b((v1 - mu) * r * load_in(g, t + 64, isbf) + load_in(b, t + 64, isbf));
}

__global__ void ln2_k(const float* __restrict__ x, const void* __restrict__ g,
                      const void* __restrict__ b, const int* __restrict__ flag,
                      __hip_bfloat16* __restrict__ y, int N) {
    int w = blockIdx.x * (blockDim.x >> 6) + (threadIdx.x >> 6);
    if (w >= N) return;
    int isbf = flag[0];
    int t = threadIdx.x & 63;
    float v0 = x[(size_t)w * F + t], v1 = x[(size_t)w * F + t + 64];
    float s = v0 + v1, sq = v0 * v0 + v1 * v1;
    for (int m = 1; m < 64; m <<= 1) { s += __shfl_xor(s, m, 64); sq += __shfl_xor(sq, m, 64); }
    float mu = s * (1.0f / F);
    float var = fmaxf(sq * (1.0f / F) - mu * mu, 0.0f);
    float r = rsqrtf(var + 1e-5f);
    y[(size_t)w * F + t]      = f2b((v0 - mu) * r * load_in(g, t, isbf) + load_in(b, t, isbf));
    y[(size_t)w * F + t + 64] = f2b((v1 - mu) * r * load_in(g, t + 64, isbf) + load_in(b, t + 64, isbf));
}

// ---------------- projection GEMM (4 waves/block, wave = 16x16 tile) ----------------
__global__ void proj_gemm_k(const __hip_bfloat16* __restrict__ X,
                            const __hip_bfloat16* __restrict__ Wh,
                            const __hip_bfloat16* __restrict__ Wt,
                            const __hip_bfloat16* __restrict__ We,
                            const float* __restrict__ head_norm,
                            __hip_bfloat16* __restrict__ fh,
                            __hip_bfloat16* __restrict__ ft,
                            float* __restrict__ fe,
                            uint32* __restrict__ fe_bf, int N) {
    int mt = blockIdx.x;
    int nt = blockIdx.y * 4 + (threadIdx.x >> 6);   // 0..23
    int lane = threadIdx.x & 63;
    int lr = lane & 15, quad = lane >> 4;
    int wsel = nt >> 3;
    const __hip_bfloat16* W = (wsel == 0) ? Wh : (wsel == 1) ? Wt : We;
    int ncol = (nt & 7) * 16 + lr;
    int mrow = mt * 16 + lr;
    if (mrow >= N) mrow = N - 1;
    f32x4 acc = {0.f, 0.f, 0.f, 0.f};
    const __hip_bfloat16* ar = X + (size_t)mrow * F + quad * 8;
    const __hip_bfloat16* br = W + (size_t)ncol * F + quad * 8;
    for (int kk = 0; kk < 4; ++kk) {
        bf16x8 af = *reinterpret_cast<const bf16x8*>(ar + kk * 32);
        bf16x8 bv = *reinterpret_cast<const bf16x8*>(br + kk * 32);
        acc = __builtin_amdgcn_mfma_f32_16x16x32_bf16(af, bv, acc, 0, 0, 0);
    }
    for (int r = 0; r < 4; ++r) {
        int row = mt * 16 + quad * 4 + r;
        if (row >= N) continue;
        float v = acc[r] * head_norm[row];
        size_t idx = (size_t)row * F + ncol;
        if (wsel == 0) fh[idx] = f2b(v);
        else if (wsel == 1) ft[idx] = f2b(v);
        else {
            fe[idx] = v;
            // packed bf16 copy for hop-0 gathers: partner col in same wave holds ncol^1
            // simpler: write scalar halves via atomic-free trick -> write bf16 into byte-addressed array
            ((__hip_bfloat16*)fe_bf)[idx] = f2b(v);
        }
    }
}

// ---------------- fused edge attention + per-(dst,head) softmax ----------------
// one wave per destination node; lane t handles feature pair (2t, 2t+1), head t>>3
__global__ void attn_soft_k(const int* __restrict__ csr_src, const int* __restrict__ row_ptr,
                            const uint32* __restrict__ fh2, const uint32* __restrict__ ft2,
                            const float* __restrict__ attn_f, const float* __restrict__ log_in,
                            float* __restrict__ e_buf, int N) {
    int w = blockIdx.x * (blockDim.x >> 6) + (threadIdx.x >> 6);
    if (w >= N) return;
    int t = threadIdx.x & 63;
    int b = row_ptr[w], e = row_ptr[w + 1];
    uint32 fp = ft2[(size_t)w * 64 + t];
    float ftl = bflo(fp), fth = bfhi(fp);
    float at0 = attn_f[2 * t], at1 = attn_f[2 * t + 1];
    float scale = log_in[w] * (1.0f / 16.0f);
    int h = t >> 3;
    float m = -1e30f;
    for (int p = b; p < e; ++p) {
        int s = csr_src[p];
        uint32 g = fh2[(size_t)s * 64 + t];
        float p0 = bflo(g) * ftl, p1 = bfhi(g) * fth;
        p0 = (p0 > 0.f ? p0 : 0.2f * p0) * at0;
        p1 = (p1 > 0.f ? p1 : 0.2f * p1) * at1;
        float r = p0 + p1;
        r += __shfl_xor(r, 1, 64);
        r += __shfl_xor(r, 2, 64);
        r += __shfl_xor(r, 4, 64);
        float logit = r * scale;          // uniform within 8-lane head group
        if ((t & 7) == 0) e_buf[(size_t)p * 8 + h] = logit;
        m = fmaxf(m, logit);
    }
    // head stats for head (t&7) live in lane (t&7)*8
    float mh = __shfl(m, (t & 7) << 3, 64);
    float sum = 0.f;
    for (size_t base = (size_t)b * 8 + t; base < (size_t)e * 8; base += 64)
        sum += expf(e_buf[base] - mh);
    sum += __shfl_xor(sum, 8, 64);
    sum += __shfl_xor(sum, 16, 64);
    sum += __shfl_xor(sum, 32, 64);      // sum over lanes with same (t&7)
    float inv = 1.0f / fmaxf(sum, 1e-30f);
    for (size_t base = (size_t)b * 8 + t; base < (size_t)e * 8; base += 64)
        e_buf[base] = expf(e_buf[base] - mh) * inv;
}

// ---------------- diffusion hop: bf16-pair gathers, fp32 accumulate ----------------
__global__ void hop_k(const uint32* __restrict__ gsrc2, const float* __restrict__ a_buf,
                      const int* __restrict__ csr_src, const int* __restrict__ row_ptr,
                      const float* __restrict__ tail_norm, const float* __restrict__ head_norm,
                      const float* __restrict__ fe, const void* __restrict__ feat,
                      const int* __restrict__ flag,
                      uint32* __restrict__ out_bf, float* __restrict__ out_f32,
                      int last, int N) {
    int w = blockIdx.x * (blockDim.x >> 6) + (threadIdx.x >> 6);
    if (w >= N) return;
    int t = threadIdx.x & 63;
    int b = row_ptr[w], e = row_ptr[w + 1];
    int h = t >> 3;
    float acc0 = 0.f, acc1 = 0.f;
    int p = b;
    for (; p + 1 < e; p += 2) {
        int s0 = csr_src[p], s1 = csr_src[p + 1];
        float a0 = a_buf[(size_t)p * 8 + h];
        float a1 = a_buf[(size_t)(p + 1) * 8 + h];
        uint32 g0 = gsrc2[(size_t)s0 * 64 + t];
        uint32 g1 = gsrc2[(size_t)s1 * 64 + t];
        acc0 += bflo(g0) * a0; acc1 += bfhi(g0) * a0;
        acc0 += bflo(g1) * a1; acc1 += bfhi(g1) * a1;
    }
    if (p < e) {
        int s0 = csr_src[p];
        float a0 = a_buf[(size_t)p * 8 + h];
        uint32 g0 = gsrc2[(size_t)s0 * 64 + t];
        acc0 += bflo(g0) * a0; acc1 += bfhi(g0) * a0;
    }
    float tl = tail_norm[w] * 0.9f;
    float2 fev = ((const float2*)fe)[(size_t)w * 64 + t];
    float r0 = tl * acc0 + 0.1f * fev.x;
    float r1 = tl * acc1 + 0.1f * fev.y;
    if (last) {
        int isbf = flag[0];
        float f0 = load_in(feat, (size_t)w * F + 2 * t, isbf);
        float f1 = load_in(feat, (size_t)w * F + 2 * t + 1, isbf);
        float2 o; o.x = r0 + f0; o.y = r1 + f1;
        ((float2*)out_f32)[(size_t)w * 64 + t] = o;
    } else {
        float hn = head_norm[w];
        out_bf[(size_t)w * 64 + t] = packbf2(r0 * hn, r1 * hn);
    }
}

// ---------------- FFN ----------------
__global__ void ff1_k(const __hip_bfloat16* __restrict__ Y, const __hip_bfloat16* __restrict__ W1,
                      const float* __restrict__ b1f, __hip_bfloat16* __restrict__ T1, int N) {
    int mt = blockIdx.x;
    int nt = blockIdx.y * 4 + (threadIdx.x >> 6);   // 0..31
    int lane = threadIdx.x & 63;
    int lr = lane & 15, quad = lane >> 4;
    int mrow = mt * 16 + lr;
    if (mrow >= N) mrow = N - 1;
    int ncol = nt * 16 + lr;
    f32x4 acc = {0.f, 0.f, 0.f, 0.f};
    const __hip_bfloat16* ar = Y + (size_t)mrow * F + quad * 8;
    const __hip_bfloat16* br = W1 + (size_t)ncol * F + quad * 8;
    for (int kk = 0; kk < 4; ++kk) {
        bf16x8 af = *reinterpret_cast<const bf16x8*>(ar + kk * 32);
        bf16x8 bv = *reinterpret_cast<const bf16x8*>(br + kk * 32);
        acc = __builtin_amdgcn_mfma_f32_16x16x32_bf16(af, bv, acc, 0, 0, 0);
    }
    float bias = b1f[ncol];
    for (int r = 0; r < 4; ++r) {
        int row = mt * 16 + quad * 4 + r;
        if (row >= N) continue;
        float v = acc[r] + bias;
        v = v > 0.f ? v : 0.f;
        T1[(size_t)row * 512 + ncol] = f2b(v);
    }
}

__global__ void ff2_k(const __hip_bfloat16* __restrict__ T1, const __hip_bfloat16* __restrict__ W2,
                      const float* __restrict__ b2f, const float* __restrict__ rst,
                      const int* __restrict__ flag, void* __restrict__ out, int N) {
    int mt = blockIdx.x;
    int nt = blockIdx.y * 4 + (threadIdx.x >> 6);   // 0..7
    int lane = threadIdx.x & 63;
    int lr = lane & 15, quad = lane >> 4;
    int mrow = mt * 16 + lr;
    if (mrow >= N) mrow = N - 1;
    int ncol = nt * 16 + lr;
    f32x4 acc = {0.f, 0.f, 0.f, 0.f};
    const __hip_bfloat16* ar = T1 + (size_t)mrow * 512 + quad * 8;
    const __hip_bfloat16* br = W2 + (size_t)ncol * 512 + quad * 8;
    for (int kk = 0; kk < 16; ++kk) {
        bf16x8 af = *reinterpret_cast<const bf16x8*>(ar + kk * 32);
        bf16x8 bv = *reinterpret_cast<const bf16x8*>(br + kk * 32);
        acc = __builtin_amdgcn_mfma_f32_16x16x32_bf16(af, bv, acc, 0, 0, 0);
    }
    int isbf = flag[0];
    float bias = b2f[ncol];
    for (int r = 0; r < 4; ++r) {
        int row = mt * 16 + quad * 4 + r;
        if (row >= N) continue;
        float v = acc[r] + bias + rst[(size_t)row * F + ncol];
        size_t idx = (size_t)row * F + ncol;
        if (isbf) ((__hip_bfloat16*)out)[idx] = f2b(v);
        else ((float*)out)[idx] = v;
    }
}

extern "C" void kernel_launch(void* const* d_in, const int* in_sizes, int n_in,
                              void* d_out, int out_size, void* d_ws, size_t ws_size,
                              hipStream_t stream) {
    if (n_in < 15) return;
    const void* feat = d_in[0];
    const int* src = (const int*)d_in[1];
    const int* dst = (const int*)d_in[2];
    const void* w_head = d_in[3];
    const void* w_tail = d_in[4];
    const void* w_ent  = d_in[5];
    const void* attn   = d_in[6];
    const void* ln1_g  = d_in[7];
    const void* ln1_b  = d_in[8];
    const void* ln2_g  = d_in[9];
    const void* ln2_b  = d_in[10];
    const void* ff_w1  = d_in[11];
    const void* ff_b1  = d_in[12];
    const void* ff_w2  = d_in[13];
    const void* ff_b2  = d_in[14];

    const int N = in_sizes[0] / F;
    const int E = in_sizes[1];
    (void)out_size;

    char* base = (char*)d_ws;
    size_t off = 0;
    auto alloc = [&](size_t bytes) -> void* {
        void* r = base + off;
        off += (bytes + 255) & ~(size_t)255;
        return r;
    };
    int* cnt3      = (int*)alloc((size_t)3 * N * 4);
    int* in_cnt = cnt3, * out_cnt = cnt3 + N, * cursor = cnt3 + 2 * N;
    int* row_ptr   = (int*)alloc((size_t)(N + 1) * 4);
    int* flag      = (int*)alloc(256);
    float* head_norm = (float*)alloc((size_t)N * 4);
    float* tail_norm = (float*)alloc((size_t)N * 4);
    float* log_in    = (float*)alloc((size_t)N * 4);
    float* attn_f    = (float*)alloc((size_t)F * 4);
    float* b1f       = (float*)alloc((size_t)512 * 4);
    float* b2f_      = (float*)alloc((size_t)F * 4);
    int* csr_src   = (int*)alloc((size_t)E * 4);
    __hip_bfloat16* wh_bf = (__hip_bfloat16*)alloc((size_t)F * F * 2);
    __hip_bfloat16* wt_bf = (__hip_bfloat16*)alloc((size_t)F * F * 2);
    __hip_bfloat16* we_bf = (__hip_bfloat16*)alloc((size_t)F * F * 2);
    __hip_bfloat16* w1_bf = (__hip_bfloat16*)alloc((size_t)512 * F * 2);
    __hip_bfloat16* w2_bf = (__hip_bfloat16*)alloc((size_t)F * 512 * 2);
    // region reused by t1 (N*512 bf16 = 51.2MB) after the graph phase:
    __hip_bfloat16* x_bf = (__hip_bfloat16*)alloc((size_t)N * F * 2);   // 12.8MB
    __hip_bfloat16* fh   = (__hip_bfloat16*)alloc((size_t)N * F * 2);   // 12.8MB
    __hip_bfloat16* ftb  = (__hip_bfloat16*)alloc((size_t)N * F * 2);   // 12.8MB
    float* e_a = (float*)alloc((size_t)E * 8 * 4);                      // 20.5MB
    __hip_bfloat16* t1 = x_bf;
    uint32* fe_bf = (uint32*)alloc((size_t)N * F * 2);   // packed bf16 pairs
    uint32* hA_bf = (uint32*)alloc((size_t)N * F * 2);
    uint32* hB_bf = (uint32*)alloc((size_t)N * F * 2);
    float* fe  = (float*)alloc((size_t)N * F * 4);
    float* rst = (float*)alloc((size_t)N * F * 4);
    __hip_bfloat16* y_bf = (__hip_bfloat16*)hA_bf;   // dead after hops
    if (off > ws_size) return;

    const int Mt = (N + 15) / 16;
    const int nodeBlocks = (N + 3) / 4;

    detect_k<<<1, 256, 0, stream>>>((const uint32*)feat, flag);
    cvt_w_k<<<(F * F + 255) / 256, 256, 0, stream>>>(w_head, wh_bf, F * F, flag);
    cvt_w_k<<<(F * F + 255) / 256, 256, 0, stream>>>(w_tail, wt_bf, F * F, flag);
    cvt_w_k<<<(F * F + 255) / 256, 256, 0, stream>>>(w_ent, we_bf, F * F, flag);
    cvt_w_k<<<(512 * F + 255) / 256, 256, 0, stream>>>(ff_w1, w1_bf, 512 * F, flag);
    cvt_w_k<<<(512 * F + 255) / 256, 256, 0, stream>>>(ff_w2, w2_bf, 512 * F, flag);
    cvt_f_k<<<1, 128, 0, stream>>>(attn, attn_f, F, flag);
    cvt_f_k<<<2, 256, 0, stream>>>(ff_b1, b1f, 512, flag);
    cvt_f_k<<<1, 128, 0, stream>>>(ff_b2, b2f_, F, flag);

    zero_ints_k<<<(3 * N + 255) / 256, 256, 0, stream>>>(cnt3, 3 * N);
    degree_k<<<(E + 255) / 256, 256, 0, stream>>>(src, dst, in_cnt, out_cnt, E);
    norms_k<<<(N + 255) / 256, 256, 0, stream>>>(in_cnt, out_cnt, head_norm, tail_norm, log_in, N);
    scan_k<<<1, 1024, 0, stream>>>(in_cnt, row_ptr, N);
    scatter_k<<<(E + 255) / 256, 256, 0, stream>>>(src, dst, row_ptr, cursor, csr_src, E);

    ln1_k<<<nodeBlocks, 256, 0, stream>>>(feat, ln1_g, ln1_b, flag, x_bf, N);
    proj_gemm_k<<<dim3(Mt, 6), 256, 0, stream>>>(x_bf, wh_bf, wt_bf, we_bf, head_norm,
                                                 fh, ftb, fe, fe_bf, N);

    attn_soft_k<<<nodeBlocks, 256, 0, stream>>>(csr_src, row_ptr, (const uint32*)fh,
                                                (const uint32*)ftb, attn_f, log_in, e_a, N);

    const uint32* gsrc = fe_bf;
    uint32* bufs[2] = {hA_bf, hB_bf};
    for (int hop = 0; hop < HOPS; ++hop) {
        int last = (hop == HOPS - 1);
        uint32* dst_bf = last ? nullptr : bufs[hop & 1];
        hop_k<<<nodeBlocks, 256, 0, stream>>>(gsrc, e_a, csr_src, row_ptr, tail_norm,
                                              head_norm, fe, feat, flag, dst_bf, rst, last, N);
        if (!last) gsrc = dst_bf;
    }

    ln2_k<<<nodeBlocks, 256, 0, stream>>>(rst, ln2_g, ln2_b, flag, y_bf, N);
    ff1_k<<<dim3(Mt, 8), 256, 0, stream>>>(y_bf, w1_bf, b1f, t1, N);
    ff2_k<<<dim3(Mt, 2), 256, 0, stream>>>(t1, w2_bf, b2f_, rst, flag, d_out, N);
}